// Round 4
// baseline (130.374 us; speedup 1.0000x reference)
//
#include <hip/hip_runtime.h>
#include <hip/hip_bf16.h>

#define T_DIM 2048
#define B_DIM 64
#define H_DIM 256
#define A_DIM 256
#define NCHG 8            // chunk-groups (grid y)
#define SUB 4             // sub-chunks per block
#define TCH 64            // t-rows per sub-chunk
#define NEG_INF -1e12f

typedef __attribute__((ext_vector_type(8))) short short8;
typedef __attribute__((ext_vector_type(4))) float f32x4;

__device__ __forceinline__ unsigned short bfbits(float f) {
    __hip_bfloat16 h = __float2bfloat16(f);
    unsigned short u;
    __builtin_memcpy(&u, &h, 2);
    return u;
}
__device__ __forceinline__ float fast_tanh(float x) {
    float e = __expf(2.0f * x);
    return 1.0f - 2.0f / (e + 1.0f);
}
__device__ __forceinline__ float fast_sigmoid(float x) {
    return 1.0f / (1.0f + __expf(-x));
}

// K0: fused WmT prep (blocks 0..255) + qs GEMV (blocks 256..319)
__global__ void prep_qs_kernel(const float* __restrict__ W_a1,
                               const float* __restrict__ input,
                               const float* __restrict__ state,
                               unsigned short* __restrict__ WmT,
                               float* __restrict__ qs) {
    __shared__ float cat[512];
    int bid = blockIdx.x, tid = threadIdx.x;
    if (bid < 256) {
        WmT[tid * 256 + bid] = bfbits(W_a1[(512 + bid) * 256 + tid]);
    } else {
        int b = bid - 256;
        cat[tid] = input[b * 256 + tid];
        cat[256 + tid] = state[b * 256 + tid];
        __syncthreads();
        int a = tid;
        float s0 = 0.f, s1 = 0.f, s2 = 0.f, s3 = 0.f;
        #pragma unroll 4
        for (int k = 0; k < 512; k += 4) {
            s0 += cat[k]     * W_a1[(k)     * 256 + a];
            s1 += cat[k + 1] * W_a1[(k + 1) * 256 + a];
            s2 += cat[k + 2] * W_a1[(k + 2) * 256 + a];
            s3 += cat[k + 3] * W_a1[(k + 3) * 256 + a];
        }
        qs[b * 256 + a] = (s0 + s1) + (s2 + s3);
    }
}

// K1: pipelined attention. grid (64, NCHG) = 512 blocks (2/CU, fully resident).
// Each block: 4 sub-chunks of 64 t-rows, double-buffered LDS slabs, reg-staged
// loads issued one sub-chunk ahead, online-softmax merge across sub-chunks.
__global__ __launch_bounds__(512, 4) void attn_kernel(
    const float* __restrict__ memory, const int* __restrict__ mask,
    const unsigned short* __restrict__ WmT,
    const float* __restrict__ qs, const float* __restrict__ w_a2,
    float* __restrict__ part_m, float* __restrict__ part_l,
    float* __restrict__ part_acc)
{
    __shared__ unsigned short slab[2][TCH * 256];   // 2 x 32 KB, XOR-swizzled bf16
    __shared__ float lpart[8 * 64];
    __shared__ float pbuf[TCH];

    int b = blockIdx.x, g = blockIdx.y;
    int tid = threadIdx.x;
    int lane = tid & 63, w = tid >> 6;
    int lr = lane & 15, lh = lane >> 4;
    int tbase = g * (SUB * TCH);
    const float* mbase = memory + (size_t)tbase * (B_DIM * H_DIM) + b * H_DIM;

    // stage geometry: thread covers rows i*8+tr (i=0..7), float4 column h4
    int tr = tid >> 6, h4 = tid & 63;
    int wsw = ((h4 * 8) ^ (tr << 4)) >> 1;          // swizzled ushort offset (row&7==tr)

    // epilogue constants: lane owns 8 a-values (rows of C)
    int wa0 = w * 32;
    float qv[2][4], wv[2][4];
    #pragma unroll
    for (int mf = 0; mf < 2; ++mf)
        #pragma unroll
        for (int r = 0; r < 4; ++r) {
            int a = wa0 + mf * 16 + lh * 4 + r;
            qv[mf][r] = qs[b * 256 + a];
            wv[mf][r] = w_a2[a];
        }

    float4 ldA[4], ldB[4];
#define LOADQ(dst, q, ibase)                                                   \
    _Pragma("unroll") for (int j = 0; j < 4; ++j) {                            \
        int row = (q) * TCH + ((ibase) + j) * 8 + tr;                          \
        dst[j] = *((const float4*)(mbase + (size_t)row * (B_DIM * H_DIM)) + h4); \
    }
#define WRITEQ(src, buf, ibase)                                                \
    _Pragma("unroll") for (int j = 0; j < 4; ++j) {                            \
        int rl = ((ibase) + j) * 8 + tr;                                       \
        ushort4 o;                                                             \
        o.x = bfbits(src[j].x); o.y = bfbits(src[j].y);                        \
        o.z = bfbits(src[j].z); o.w = bfbits(src[j].w);                        \
        *(ushort4*)(&slab[buf][rl * 256 + wsw]) = o;                           \
    }

    // prologue: fill buf0, issue first half of sub-chunk 1
    LOADQ(ldA, 0, 0)
    LOADQ(ldB, 0, 4)
    WRITEQ(ldA, 0, 0)
    WRITEQ(ldB, 0, 4)
    LOADQ(ldA, 1, 0)
    __syncthreads();

    float a8[8] = {0.f, 0.f, 0.f, 0.f, 0.f, 0.f, 0.f, 0.f};
    float M = -3.4e38f, L = 0.f;
    int oct = tid & 31, slice = tid >> 5;
    int h0 = oct * 8;

    for (int s = 0; s < SUB; ++s) {
        int buf = s & 1;

        // ---- MFMA: C[a][t] over slab[buf] ----
        f32x4 acc[2][4];
        #pragma unroll
        for (int mf = 0; mf < 2; ++mf)
            #pragma unroll
            for (int nf = 0; nf < 4; ++nf)
                acc[mf][nf] = (f32x4){0.f, 0.f, 0.f, 0.f};
        #pragma unroll
        for (int kk = 0; kk < 8; ++kk) {
            short8 afr[2];
            #pragma unroll
            for (int mf = 0; mf < 2; ++mf) {
                int a = wa0 + mf * 16 + lr;
                afr[mf] = *(const short8*)(WmT + a * 256 + kk * 32 + lh * 8);
            }
            int kbyte = kk * 64 + lh * 16;
            #pragma unroll
            for (int nf = 0; nf < 4; ++nf) {
                int t = nf * 16 + lr;
                int sw = kbyte ^ ((t & 7) << 4);
                short8 bfr = *(const short8*)(&slab[buf][t * 256 + (sw >> 1)]);
                #pragma unroll
                for (int mf = 0; mf < 2; ++mf)
                    acc[mf][nf] = __builtin_amdgcn_mfma_f32_16x16x32_bf16(afr[mf], bfr, acc[mf][nf], 0, 0, 0);
            }
        }

        // issue 2nd half of next sub-chunk (hides under epi/softmax/PV)
        if (s < SUB - 1) { LOADQ(ldB, s + 1, 4) }

        // ---- epilogue: per-lane reduce over a, 2 shuffles over lh ----
        #pragma unroll
        for (int nf = 0; nf < 4; ++nf) {
            float sv = 0.f;
            #pragma unroll
            for (int mf = 0; mf < 2; ++mf)
                #pragma unroll
                for (int r = 0; r < 4; ++r)
                    sv += wv[mf][r] * fast_tanh(qv[mf][r] + acc[mf][nf][r]);
            sv += __shfl_xor(sv, 16);
            sv += __shfl_xor(sv, 32);
            if (lh == 0) lpart[w * 64 + nf * 16 + lr] = sv;
        }
        __syncthreads();

        // ---- combine wave partials + mask + redundant per-wave softmax ----
        float lg = 0.f;
        #pragma unroll
        for (int ww = 0; ww < 8; ++ww) lg += lpart[ww * 64 + lane];
        int tglob = tbase + s * TCH + lane;
        lg = mask[tglob * B_DIM + b] ? lg : NEG_INF;
        if (w == 0) pbuf[lane] = lg;
        float mx = lg;
        #pragma unroll
        for (int d = 1; d < 64; d <<= 1) mx = fmaxf(mx, __shfl_xor(mx, d));
        float ex = __expf(lg - mx);
        float sm = ex;
        #pragma unroll
        for (int d = 1; d < 64; d <<= 1) sm += __shfl_xor(sm, d);

        // online-softmax merge scalars (identical on every thread)
        float newM = fmaxf(M, mx);
        float fo = __expf(M - newM);
        L = L * fo + sm * __expf(mx - newM);
        M = newM;
        #pragma unroll
        for (int j = 0; j < 8; ++j) a8[j] *= fo;
        __syncthreads();

        // ---- PV: accumulate p*mem into regs ----
        #pragma unroll
        for (int tt = 0; tt < 4; ++tt) {
            int tl = slice * 4 + tt;
            float pt = __expf(pbuf[tl] - M);
            int swb = (h0 * 2) ^ ((tl & 7) << 4);
            uint4 u = *(const uint4*)(&slab[buf][tl * 256 + (swb >> 1)]);
            a8[0] += pt * __uint_as_float(u.x << 16);
            a8[1] += pt * __uint_as_float(u.x & 0xFFFF0000u);
            a8[2] += pt * __uint_as_float(u.y << 16);
            a8[3] += pt * __uint_as_float(u.y & 0xFFFF0000u);
            a8[4] += pt * __uint_as_float(u.z << 16);
            a8[5] += pt * __uint_as_float(u.z & 0xFFFF0000u);
            a8[6] += pt * __uint_as_float(u.w << 16);
            a8[7] += pt * __uint_as_float(u.w & 0xFFFF0000u);
        }

        // ---- write next sub-chunk into idle buffer, issue one further ahead ----
        if (s < SUB - 1) {
            WRITEQ(ldA, buf ^ 1, 0)
            WRITEQ(ldB, buf ^ 1, 4)
            if (s < SUB - 2) { LOADQ(ldA, s + 2, 0) }
        }
        __syncthreads();
    }

    // ---- final combine: alias acc2 over slab[0] (dead now) ----
    float* acc2 = (float*)&slab[0][0];             // 16 KB
    *(float4*)(&acc2[slice * 256 + h0])     = (float4){a8[0], a8[1], a8[2], a8[3]};
    *(float4*)(&acc2[slice * 256 + h0 + 4]) = (float4){a8[4], a8[5], a8[6], a8[7]};
    __syncthreads();
    int pidx = g * B_DIM + b;
    if (tid < 256) {
        float ssum = 0.f;
        #pragma unroll
        for (int sl = 0; sl < 16; ++sl) ssum += acc2[sl * 256 + tid];
        part_acc[(size_t)pidx * 256 + tid] = ssum;
    }
    if (tid == 0) { part_m[pidx] = M; part_l[pidx] = L; }
#undef LOADQ
#undef WRITEQ
}

// K2: fused merge (8 group-partials -> attn row) + gate GEMV. block = one b.
__global__ void mergegate_kernel(const float* __restrict__ part_m,
                                 const float* __restrict__ part_l,
                                 const float* __restrict__ part_acc,
                                 const float* __restrict__ input,
                                 const float* __restrict__ W_gate,
                                 float* __restrict__ gated) {
    __shared__ float ni[512];
    int b = blockIdx.x, tid = threadIdx.x;
    if (tid >= 256) {
        int k = tid - 256;
        ni[k] = input[b * 256 + k];
    } else {
        int h = tid;
        float M = -3.4e38f;
        #pragma unroll
        for (int c = 0; c < NCHG; ++c) M = fmaxf(M, part_m[c * 64 + b]);
        float L = 0.f, s = 0.f;
        #pragma unroll
        for (int c = 0; c < NCHG; ++c) {
            float sc = __expf(part_m[c * 64 + b] - M);
            L += part_l[c * 64 + b] * sc;
            s += sc * part_acc[(size_t)(c * 64 + b) * 256 + h];
        }
        ni[256 + h] = s / L;
    }
    __syncthreads();
    int j = tid;
    float s0 = 0.f, s1 = 0.f, s2 = 0.f, s3 = 0.f;
    #pragma unroll 4
    for (int k = 0; k < 512; k += 4) {
        s0 += ni[k]     * W_gate[(k)     * 512 + j];
        s1 += ni[k + 1] * W_gate[(k + 1) * 512 + j];
        s2 += ni[k + 2] * W_gate[(k + 2) * 512 + j];
        s3 += ni[k + 3] * W_gate[(k + 3) * 512 + j];
    }
    float s = (s0 + s1) + (s2 + s3);
    gated[b * 512 + j] = ni[j] * fast_sigmoid(s);
}

// K3: GRU cell. grid 256 = (16 b-tiles x 16 h-tiles), block 768.
__global__ __launch_bounds__(768) void gru_kernel(
    const float* __restrict__ gated, const float* __restrict__ state,
    const float* __restrict__ W_ih, const float* __restrict__ W_hh,
    const float* __restrict__ b_ih, const float* __restrict__ b_hh,
    float* __restrict__ out) {
    __shared__ float ld_g[4][512];
    __shared__ float ld_s[4][256];
    __shared__ float xi[3][16][4];
    __shared__ float xh[3][16][4];
    int ht = blockIdx.x & 15, bt = blockIdx.x >> 4;
    int tid = threadIdx.x;
    #pragma unroll
    for (int i = 0; i < 3; ++i) {
        int idx = i * 768 + tid;
        if (idx < 2048) ld_g[idx >> 9][idx & 511] = gated[(bt * 4 + (idx >> 9)) * 512 + (idx & 511)];
    }
    #pragma unroll
    for (int i = 0; i < 2; ++i) {
        int idx = i * 768 + tid;
        if (idx < 1024) ld_s[idx >> 8][idx & 255] = state[(bt * 4 + (idx >> 8)) * 256 + (idx & 255)];
    }

    int gid = tid >> 4, lk = tid & 15;
    int gate = gid >> 4, hl = gid & 15;
    int j = gate * 256 + ht * 16 + hl;

    float4 wi[8], wh[4];
    #pragma unroll
    for (int it = 0; it < 8; ++it)
        wi[it] = *(const float4*)(W_ih + (size_t)j * 512 + it * 64 + lk * 4);
    #pragma unroll
    for (int it = 0; it < 4; ++it)
        wh[it] = *(const float4*)(W_hh + (size_t)j * 256 + it * 64 + lk * 4);
    float bi = b_ih[j], bh = b_hh[j];
    __syncthreads();

    #pragma unroll
    for (int bb = 0; bb < 4; ++bb) {
        float g0 = 0.f, g1 = 0.f;
        #pragma unroll
        for (int it = 0; it < 8; ++it) {
            float4 gv = *(const float4*)(&ld_g[bb][it * 64 + lk * 4]);
            g0 += wi[it].x * gv.x + wi[it].z * gv.z;
            g1 += wi[it].y * gv.y + wi[it].w * gv.w;
        }
        float h0 = 0.f, h1 = 0.f;
        #pragma unroll
        for (int it = 0; it < 4; ++it) {
            float4 sv = *(const float4*)(&ld_s[bb][it * 64 + lk * 4]);
            h0 += wh[it].x * sv.x + wh[it].z * sv.z;
            h1 += wh[it].y * sv.y + wh[it].w * sv.w;
        }
        float gi_ = g0 + g1, gh_ = h0 + h1;
        #pragma unroll
        for (int m = 1; m < 16; m <<= 1) {
            gi_ += __shfl_xor(gi_, m);
            gh_ += __shfl_xor(gh_, m);
        }
        if (lk == 0) { xi[gate][hl][bb] = gi_ + bi; xh[gate][hl][bb] = gh_ + bh; }
    }
    __syncthreads();
    if (tid < 64) {
        int bb = tid >> 4, hl2 = tid & 15;
        float ir = xi[0][hl2][bb], hr = xh[0][hl2][bb];
        float iz = xi[1][hl2][bb], hz = xh[1][hl2][bb];
        float in_ = xi[2][hl2][bb], hn = xh[2][hl2][bb];
        float r = fast_sigmoid(ir + hr);
        float z = fast_sigmoid(iz + hz);
        float n = fast_tanh(in_ + r * hn);
        out[(bt * 4 + bb) * 256 + ht * 16 + hl2] =
            (1.f - z) * n + z * ld_s[bb][ht * 16 + hl2];
    }
}

extern "C" void kernel_launch(void* const* d_in, const int* in_sizes, int n_in,
                              void* d_out, int out_size, void* d_ws, size_t ws_size,
                              hipStream_t stream) {
    const float* input  = (const float*)d_in[0];
    const float* memory = (const float*)d_in[1];
    const int*   mask   = (const int*)d_in[2];
    const float* state  = (const float*)d_in[3];
    const float* W_a1   = (const float*)d_in[4];
    const float* w_a2   = (const float*)d_in[5];
    const float* W_gate = (const float*)d_in[6];
    const float* W_ih   = (const float*)d_in[7];
    const float* W_hh   = (const float*)d_in[8];
    const float* b_ih   = (const float*)d_in[9];
    const float* b_hh   = (const float*)d_in[10];
    float* out = (float*)d_out;

    char* ws = (char*)d_ws;
    unsigned short* WmT = (unsigned short*)(ws + 0);        // 131072 B
    float* qs       = (float*)(ws + 131072);                // 65536 B
    float* gated    = (float*)(ws + 196608);                // 131072 B
    float* part_m   = (float*)(ws + 327680);                // 2048 B
    float* part_l   = (float*)(ws + 331776);                // 2048 B
    float* part_acc = (float*)(ws + 335872);                // 524288 B

    prep_qs_kernel<<<320, 256, 0, stream>>>(W_a1, input, state, WmT, qs);
    attn_kernel<<<dim3(B_DIM, NCHG), 512, 0, stream>>>(
        memory, mask, WmT, qs, w_a2, part_m, part_l, part_acc);
    mergegate_kernel<<<64, 512, 0, stream>>>(part_m, part_l, part_acc, input, W_gate, gated);
    gru_kernel<<<256, 768, 0, stream>>>(gated, state, W_ih, W_hh, b_ih, b_hh, out);
}

// Round 5
// 93.536 us; speedup vs baseline: 1.3938x; 1.3938x over previous
//
#include <hip/hip_runtime.h>
#include <hip/hip_bf16.h>

#define B_DIM 64
#define H_DIM 256
#define NCHG 4            // persistent groups (grid y)
#define CHUNKS 8          // chunks per block
#define TCH 64            // t-rows per chunk
#define NEG_INF -1e12f

typedef __attribute__((ext_vector_type(8))) short short8;
typedef __attribute__((ext_vector_type(4))) float f32x4;

typedef const __attribute__((address_space(1))) void gas_void;
typedef __attribute__((address_space(3))) void las_void;

__device__ __forceinline__ unsigned short bfbits(float f) {
    __hip_bfloat16 h = __float2bfloat16(f);
    unsigned short u;
    __builtin_memcpy(&u, &h, 2);
    return u;
}
__device__ __forceinline__ float fast_tanh(float x) {
    float e = __expf(2.0f * x);
    return 1.0f - 2.0f / (e + 1.0f);
}
__device__ __forceinline__ float fast_sigmoid(float x) {
    return 1.0f / (1.0f + __expf(-x));
}

// K0: fused WmT prep (blocks 0..255) + qs GEMV (blocks 256..319)
__global__ void prep_qs_kernel(const float* __restrict__ W_a1,
                               const float* __restrict__ input,
                               const float* __restrict__ state,
                               unsigned short* __restrict__ WmT,
                               float* __restrict__ qs) {
    __shared__ float cat[512];
    int bid = blockIdx.x, tid = threadIdx.x;
    if (bid < 256) {
        WmT[tid * 256 + bid] = bfbits(W_a1[(512 + bid) * 256 + tid]);
    } else {
        int b = bid - 256;
        cat[tid] = input[b * 256 + tid];
        cat[256 + tid] = state[b * 256 + tid];
        __syncthreads();
        int a = tid;
        float s0 = 0.f, s1 = 0.f, s2 = 0.f, s3 = 0.f;
        #pragma unroll 4
        for (int k = 0; k < 512; k += 4) {
            s0 += cat[k]     * W_a1[(k)     * 256 + a];
            s1 += cat[k + 1] * W_a1[(k + 1) * 256 + a];
            s2 += cat[k + 2] * W_a1[(k + 2) * 256 + a];
            s3 += cat[k + 3] * W_a1[(k + 3) * 256 + a];
        }
        qs[b * 256 + a] = (s0 + s1) + (s2 + s3);
    }
}

// K1: persistent pipelined attention. grid (64, 4) = 256 blocks = 1/CU.
// Per chunk: convert f32LDS->bf16LDS | prefetch next chunk via global_load_lds
// (overlaps MFMA+epilogue) | MFMA logits | softmax merge | PV.
// All LDS tiles carry the 16B-slot XOR swizzle byte^=((row&7)<<4); the f32
// slab gets it via pre-swizzled GLOBAL source addresses (gll writes linearly).
__global__ __launch_bounds__(512, 1) void attn_kernel(
    const float* __restrict__ memory, const int* __restrict__ mask,
    const unsigned short* __restrict__ WmT,
    const float* __restrict__ qs, const float* __restrict__ w_a2,
    float* __restrict__ part_m, float* __restrict__ part_l,
    float* __restrict__ part_acc)
{
    extern __shared__ char smem[];
    float* slabF = (float*)smem;                                  // [64][256] f32  (64 KB)
    unsigned short* slabB = (unsigned short*)(smem + 65536);      // [64][256] bf16 (32 KB)
    float* lpart = (float*)(smem + 65536 + 32768);                // [8][64]
    float* pbuf  = lpart + 512;                                   // [64]

    int b = blockIdx.x, g = blockIdx.y;
    int tid = threadIdx.x;
    int lane = tid & 63, w = tid >> 6;
    int lr = lane & 15, lh = lane >> 4;
    int tbase = g * (CHUNKS * TCH);
    const char* mbase = (const char*)(memory + (size_t)tbase * (B_DIM * H_DIM) + b * H_DIM);

    // epilogue constants: lane owns 8 a-values (C rows)
    int wa0 = w * 32;
    float qv[2][4], wv[2][4];
    #pragma unroll
    for (int mf = 0; mf < 2; ++mf)
        #pragma unroll
        for (int r = 0; r < 4; ++r) {
            int a = wa0 + mf * 16 + lh * 4 + r;
            qv[mf][r] = qs[b * 256 + a];
            wv[mf][r] = w_a2[a];
        }

    // prefetch chunk s into slabF: wave w loads rows w*8+i (1 KB = 64 lanes x 16B)
    auto stage = [&](int s) {
        #pragma unroll
        for (int i = 0; i < 8; ++i) {
            int row = w * 8 + i;
            const char* gp = mbase + (size_t)(s * TCH + row) * (B_DIM * H_DIM * 4)
                           + ((lane * 16) ^ ((row & 7) << 4));
            __builtin_amdgcn_global_load_lds((gas_void*)gp,
                                             (las_void*)&slabF[row * 256], 16, 0, 0);
        }
    };

    stage(0);
    __syncthreads();   // drains vmcnt -> chunk 0 resident

    float a8[8] = {0.f, 0.f, 0.f, 0.f, 0.f, 0.f, 0.f, 0.f};
    float M = -3.4e38f, L = 0.f;
    int oct = tid & 31, slice = tid >> 5;
    int h0 = oct * 8;
    int crow = tid & 63, cseg = tid >> 6;              // convert mapping
    int csw = (crow & 7) << 4;

    for (int s = 0; s < CHUNKS; ++s) {
        // ---- convert slabF(s) -> slabB (both XOR-swizzled) ----
        #pragma unroll
        for (int j = 0; j < 4; ++j) {
            int k0 = cseg * 32 + j * 8;                // 8 consecutive f32
            float4 v0 = *(const float4*)((const char*)(slabF + crow * 256) + (((k0 * 4))      ^ csw));
            float4 v1 = *(const float4*)((const char*)(slabF + crow * 256) + (((k0 * 4) + 16) ^ csw));
            ushort4 o0, o1;
            o0.x = bfbits(v0.x); o0.y = bfbits(v0.y); o0.z = bfbits(v0.z); o0.w = bfbits(v0.w);
            o1.x = bfbits(v1.x); o1.y = bfbits(v1.y); o1.z = bfbits(v1.z); o1.w = bfbits(v1.w);
            *(ushort4*)((char*)(slabB + crow * 256) + ((k0 * 2) ^ csw))     = o0;
            *(ushort4*)((char*)(slabB + crow * 256) + (((k0 * 2) + 8) ^ ((csw & 8) ? csw : csw))) = o1;
        }
        __syncthreads();   // slabB ready, slabF free

        if (s < CHUNKS - 1) stage(s + 1);   // async; drains at next barrier

        // ---- MFMA: C[a][t] over slabB ----
        f32x4 acc[2][4];
        #pragma unroll
        for (int mf = 0; mf < 2; ++mf)
            #pragma unroll
            for (int nf = 0; nf < 4; ++nf)
                acc[mf][nf] = (f32x4){0.f, 0.f, 0.f, 0.f};
        #pragma unroll
        for (int kk = 0; kk < 8; ++kk) {
            short8 afr[2];
            #pragma unroll
            for (int mf = 0; mf < 2; ++mf) {
                int a = wa0 + mf * 16 + lr;
                afr[mf] = *(const short8*)(WmT + a * 256 + kk * 32 + lh * 8);
            }
            int kbyte = kk * 64 + lh * 16;
            #pragma unroll
            for (int nf = 0; nf < 4; ++nf) {
                int t = nf * 16 + lr;
                int sw = kbyte ^ ((t & 7) << 4);
                short8 bfr = *(const short8*)((const char*)(slabB + t * 256) + sw);
                #pragma unroll
                for (int mf = 0; mf < 2; ++mf)
                    acc[mf][nf] = __builtin_amdgcn_mfma_f32_16x16x32_bf16(afr[mf], bfr, acc[mf][nf], 0, 0, 0);
            }
        }

        // ---- epilogue: per-lane reduce over a, 2 shuffles over lh ----
        #pragma unroll
        for (int nf = 0; nf < 4; ++nf) {
            float sv = 0.f;
            #pragma unroll
            for (int mf = 0; mf < 2; ++mf)
                #pragma unroll
                for (int r = 0; r < 4; ++r)
                    sv += wv[mf][r] * fast_tanh(qv[mf][r] + acc[mf][nf][r]);
            sv += __shfl_xor(sv, 16);
            sv += __shfl_xor(sv, 32);
            if (lh == 0) lpart[w * 64 + nf * 16 + lr] = sv;
        }
        __syncthreads();   // lpart ready (also drains the prefetch)

        // ---- combine wave partials + mask + redundant all-wave softmax ----
        float lg = 0.f;
        #pragma unroll
        for (int ww = 0; ww < 8; ++ww) lg += lpart[ww * 64 + lane];
        int tglob = tbase + s * TCH + lane;
        lg = mask[tglob * B_DIM + b] ? lg : NEG_INF;
        if (w == 0) pbuf[lane] = lg;
        float mx = lg;
        #pragma unroll
        for (int d = 1; d < 64; d <<= 1) mx = fmaxf(mx, __shfl_xor(mx, d));
        float ex = __expf(lg - mx);
        float sm = ex;
        #pragma unroll
        for (int d = 1; d < 64; d <<= 1) sm += __shfl_xor(sm, d);

        float newM = fmaxf(M, mx);
        float fo = __expf(M - newM);
        L = L * fo + sm * __expf(mx - newM);
        M = newM;
        #pragma unroll
        for (int j = 0; j < 8; ++j) a8[j] *= fo;
        __syncthreads();   // pbuf visible

        // ---- PV: accumulate p * mem into regs (from slabB) ----
        #pragma unroll
        for (int tt = 0; tt < 4; ++tt) {
            int tl = slice * 4 + tt;
            float pt = __expf(pbuf[tl] - M);
            int swb = (h0 * 2) ^ ((tl & 7) << 4);
            uint4 u = *(const uint4*)((const char*)(slabB + tl * 256) + swb);
            a8[0] += pt * __uint_as_float(u.x << 16);
            a8[1] += pt * __uint_as_float(u.x & 0xFFFF0000u);
            a8[2] += pt * __uint_as_float(u.y << 16);
            a8[3] += pt * __uint_as_float(u.y & 0xFFFF0000u);
            a8[4] += pt * __uint_as_float(u.z << 16);
            a8[5] += pt * __uint_as_float(u.z & 0xFFFF0000u);
            a8[6] += pt * __uint_as_float(u.w << 16);
            a8[7] += pt * __uint_as_float(u.w & 0xFFFF0000u);
        }
        __syncthreads();   // PV done; next convert may overwrite slabB
    }

    // ---- final combine: alias acc2 over slabF (dead now) ----
    float* acc2 = (float*)slabF;                    // [16][256]
    *(float4*)(&acc2[slice * 256 + h0])     = (float4){a8[0], a8[1], a8[2], a8[3]};
    *(float4*)(&acc2[slice * 256 + h0 + 4]) = (float4){a8[4], a8[5], a8[6], a8[7]};
    __syncthreads();
    int pidx = g * B_DIM + b;
    if (tid < 256) {
        float ssum = 0.f;
        #pragma unroll
        for (int sl = 0; sl < 16; ++sl) ssum += acc2[sl * 256 + tid];
        part_acc[(size_t)pidx * 256 + tid] = ssum;
    }
    if (tid == 0) { part_m[pidx] = M; part_l[pidx] = L; }
}

// K2: fused merge (4 group-partials -> attn row) + gate GEMV. block = one b.
__global__ void mergegate_kernel(const float* __restrict__ part_m,
                                 const float* __restrict__ part_l,
                                 const float* __restrict__ part_acc,
                                 const float* __restrict__ input,
                                 const float* __restrict__ W_gate,
                                 float* __restrict__ gated) {
    __shared__ float ni[512];
    int b = blockIdx.x, tid = threadIdx.x;
    if (tid >= 256) {
        int k = tid - 256;
        ni[k] = input[b * 256 + k];
    } else {
        int h = tid;
        float M = -3.4e38f;
        #pragma unroll
        for (int c = 0; c < NCHG; ++c) M = fmaxf(M, part_m[c * 64 + b]);
        float L = 0.f, s = 0.f;
        #pragma unroll
        for (int c = 0; c < NCHG; ++c) {
            float sc = __expf(part_m[c * 64 + b] - M);
            L += part_l[c * 64 + b] * sc;
            s += sc * part_acc[(size_t)(c * 64 + b) * 256 + h];
        }
        ni[256 + h] = s / L;
    }
    __syncthreads();
    int j = tid;
    float s0 = 0.f, s1 = 0.f, s2 = 0.f, s3 = 0.f;
    #pragma unroll 4
    for (int k = 0; k < 512; k += 4) {
        s0 += ni[k]     * W_gate[(k)     * 512 + j];
        s1 += ni[k + 1] * W_gate[(k + 1) * 512 + j];
        s2 += ni[k + 2] * W_gate[(k + 2) * 512 + j];
        s3 += ni[k + 3] * W_gate[(k + 3) * 512 + j];
    }
    float s = (s0 + s1) + (s2 + s3);
    gated[b * 512 + j] = ni[j] * fast_sigmoid(s);
}

// K3: GRU cell. grid 256 = (16 b-tiles x 16 h-tiles), block 768.
__global__ __launch_bounds__(768) void gru_kernel(
    const float* __restrict__ gated, const float* __restrict__ state,
    const float* __restrict__ W_ih, const float* __restrict__ W_hh,
    const float* __restrict__ b_ih, const float* __restrict__ b_hh,
    float* __restrict__ out) {
    __shared__ float ld_g[4][512];
    __shared__ float ld_s[4][256];
    __shared__ float xi[3][16][4];
    __shared__ float xh[3][16][4];
    int ht = blockIdx.x & 15, bt = blockIdx.x >> 4;
    int tid = threadIdx.x;
    #pragma unroll
    for (int i = 0; i < 3; ++i) {
        int idx = i * 768 + tid;
        if (idx < 2048) ld_g[idx >> 9][idx & 511] = gated[(bt * 4 + (idx >> 9)) * 512 + (idx & 511)];
    }
    #pragma unroll
    for (int i = 0; i < 2; ++i) {
        int idx = i * 768 + tid;
        if (idx < 1024) ld_s[idx >> 8][idx & 255] = state[(bt * 4 + (idx >> 8)) * 256 + (idx & 255)];
    }

    int gid = tid >> 4, lk = tid & 15;
    int gate = gid >> 4, hl = gid & 15;
    int j = gate * 256 + ht * 16 + hl;

    float4 wi[8], wh[4];
    #pragma unroll
    for (int it = 0; it < 8; ++it)
        wi[it] = *(const float4*)(W_ih + (size_t)j * 512 + it * 64 + lk * 4);
    #pragma unroll
    for (int it = 0; it < 4; ++it)
        wh[it] = *(const float4*)(W_hh + (size_t)j * 256 + it * 64 + lk * 4);
    float bi = b_ih[j], bh = b_hh[j];
    __syncthreads();

    #pragma unroll
    for (int bb = 0; bb < 4; ++bb) {
        float g0 = 0.f, g1 = 0.f;
        #pragma unroll
        for (int it = 0; it < 8; ++it) {
            float4 gv = *(const float4*)(&ld_g[bb][it * 64 + lk * 4]);
            g0 += wi[it].x * gv.x + wi[it].z * gv.z;
            g1 += wi[it].y * gv.y + wi[it].w * gv.w;
        }
        float h0 = 0.f, h1 = 0.f;
        #pragma unroll
        for (int it = 0; it < 4; ++it) {
            float4 sv = *(const float4*)(&ld_s[bb][it * 64 + lk * 4]);
            h0 += wh[it].x * sv.x + wh[it].z * sv.z;
            h1 += wh[it].y * sv.y + wh[it].w * sv.w;
        }
        float gi_ = g0 + g1, gh_ = h0 + h1;
        #pragma unroll
        for (int m = 1; m < 16; m <<= 1) {
            gi_ += __shfl_xor(gi_, m);
            gh_ += __shfl_xor(gh_, m);
        }
        if (lk == 0) { xi[gate][hl][bb] = gi_ + bi; xh[gate][hl][bb] = gh_ + bh; }
    }
    __syncthreads();
    if (tid < 64) {
        int bb = tid >> 4, hl2 = tid & 15;
        float ir = xi[0][hl2][bb], hr = xh[0][hl2][bb];
        float iz = xi[1][hl2][bb], hz = xh[1][hl2][bb];
        float in_ = xi[2][hl2][bb], hn = xh[2][hl2][bb];
        float r = fast_sigmoid(ir + hr);
        float z = fast_sigmoid(iz + hz);
        float n = fast_tanh(in_ + r * hn);
        out[(bt * 4 + bb) * 256 + ht * 16 + hl2] =
            (1.f - z) * n + z * ld_s[bb][ht * 16 + hl2];
    }
}

extern "C" void kernel_launch(void* const* d_in, const int* in_sizes, int n_in,
                              void* d_out, int out_size, void* d_ws, size_t ws_size,
                              hipStream_t stream) {
    const float* input  = (const float*)d_in[0];
    const float* memory = (const float*)d_in[1];
    const int*   mask   = (const int*)d_in[2];
    const float* state  = (const float*)d_in[3];
    const float* W_a1   = (const float*)d_in[4];
    const float* w_a2   = (const float*)d_in[5];
    const float* W_gate = (const float*)d_in[6];
    const float* W_ih   = (const float*)d_in[7];
    const float* W_hh   = (const float*)d_in[8];
    const float* b_ih   = (const float*)d_in[9];
    const float* b_hh   = (const float*)d_in[10];
    float* out = (float*)d_out;

    char* ws = (char*)d_ws;
    unsigned short* WmT = (unsigned short*)(ws + 0);        // 131072 B
    float* qs       = (float*)(ws + 131072);                // 65536 B
    float* gated    = (float*)(ws + 196608);                // 131072 B
    float* part_m   = (float*)(ws + 327680);                // 1024 B
    float* part_l   = (float*)(ws + 331776);                // 1024 B
    float* part_acc = (float*)(ws + 335872);                // 262144 B

    prep_qs_kernel<<<320, 256, 0, stream>>>(W_a1, input, state, WmT, qs);

    (void)hipFuncSetAttribute((const void*)attn_kernel,
                              hipFuncAttributeMaxDynamicSharedMemorySize, 101376);
    attn_kernel<<<dim3(B_DIM, NCHG), 512, 101376, stream>>>(
        memory, mask, WmT, qs, w_a2, part_m, part_l, part_acc);

    mergegate_kernel<<<64, 512, 0, stream>>>(part_m, part_l, part_acc, input, W_gate, gated);
    gru_kernel<<<256, 768, 0, stream>>>(gated, state, W_ih, W_hh, b_ih, b_hh, out);
}

// Round 6
// 85.290 us; speedup vs baseline: 1.5286x; 1.0967x over previous
//
#include <hip/hip_runtime.h>
#include <hip/hip_bf16.h>

#define B_DIM 64
#define H_DIM 256
#define NCHG 4            // persistent groups (grid y)
#define CHUNKS 8          // chunks per block
#define TCH 64            // t-rows per chunk
#define NEG_INF -1e12f

typedef __attribute__((ext_vector_type(8))) short short8;
typedef __attribute__((ext_vector_type(4))) float f32x4;

__device__ __forceinline__ unsigned short bfbits(float f) {
    __hip_bfloat16 h = __float2bfloat16(f);
    unsigned short u;
    __builtin_memcpy(&u, &h, 2);
    return u;
}
__device__ __forceinline__ float fast_tanh(float x) {
    float e = __expf(2.0f * x);
    return 1.0f - 2.0f / (e + 1.0f);
}
__device__ __forceinline__ float fast_sigmoid(float x) {
    return 1.0f / (1.0f + __expf(-x));
}

// K0: fused WmT prep (blocks 0..255) + qs GEMV (blocks 256..319)
__global__ void prep_qs_kernel(const float* __restrict__ W_a1,
                               const float* __restrict__ input,
                               const float* __restrict__ state,
                               unsigned short* __restrict__ WmT,
                               float* __restrict__ qs) {
    __shared__ float cat[512];
    int bid = blockIdx.x, tid = threadIdx.x;
    if (bid < 256) {
        WmT[tid * 256 + bid] = bfbits(W_a1[(512 + bid) * 256 + tid]);
    } else {
        int b = bid - 256;
        cat[tid] = input[b * 256 + tid];
        cat[256 + tid] = state[b * 256 + tid];
        __syncthreads();
        int a = tid;
        float s0 = 0.f, s1 = 0.f, s2 = 0.f, s3 = 0.f;
        #pragma unroll 4
        for (int k = 0; k < 512; k += 4) {
            s0 += cat[k]     * W_a1[(k)     * 256 + a];
            s1 += cat[k + 1] * W_a1[(k + 1) * 256 + a];
            s2 += cat[k + 2] * W_a1[(k + 2) * 256 + a];
            s3 += cat[k + 3] * W_a1[(k + 3) * 256 + a];
        }
        qs[b * 256 + a] = (s0 + s1) + (s2 + s3);
    }
}

// K1: persistent attention, reg-resident Wm A-fragments, reg-staged slab,
// 2 barriers per chunk. grid (64, 4) = 256 blocks = 1/CU.
__global__ __launch_bounds__(512, 2) void attn_kernel(
    const float* __restrict__ memory, const int* __restrict__ mask,
    const unsigned short* __restrict__ WmT,
    const float* __restrict__ qs, const float* __restrict__ w_a2,
    float* __restrict__ part_m, float* __restrict__ part_l,
    float* __restrict__ part_acc)
{
    extern __shared__ char smem[];
    unsigned short* slab0 = (unsigned short*)smem;            // [64][256] bf16, swizzled
    unsigned short* slab1 = (unsigned short*)(smem + 32768);
    float* lpart = (float*)(smem + 65536);                    // [8][64]
    int*   maskL = (int*)(smem + 65536 + 2048);               // [512]

    int b = blockIdx.x, g = blockIdx.y;
    int tid = threadIdx.x;
    int lane = tid & 63, w = tid >> 6;
    int lr = lane & 15, lh = lane >> 4;
    int tbase = g * (CHUNKS * TCH);
    const float* mbase = memory + (size_t)tbase * (B_DIM * H_DIM) + b * H_DIM;

    // ---- one-time preloads ----
    // chunk-0 staging (thread covers rows i*8+w, float4 column = lane)
    float4 ld[8];
    #pragma unroll
    for (int i = 0; i < 8; ++i)
        ld[i] = *((const float4*)(mbase + (size_t)(i * 8 + w) * (B_DIM * H_DIM)) + lane);

    // Wm A-fragments -> 64 persistent VGPRs (wave owns a in [w*32, w*32+32))
    int wa0 = w * 32;
    short8 areg[8][2];
    #pragma unroll
    for (int kk = 0; kk < 8; ++kk)
        #pragma unroll
        for (int mf = 0; mf < 2; ++mf)
            areg[kk][mf] = *(const short8*)(WmT + (wa0 + mf * 16 + lr) * 256 + kk * 32 + lh * 8);

    // epilogue constants (lane owns 8 a-values = C rows)
    float qv[2][4], wv[2][4];
    #pragma unroll
    for (int mf = 0; mf < 2; ++mf)
        #pragma unroll
        for (int r = 0; r < 4; ++r) {
            int a = wa0 + mf * 16 + lh * 4 + r;
            qv[mf][r] = qs[b * 256 + a];
            wv[mf][r] = w_a2[a];
        }

    // mask slice for this block (one strided load, once)
    maskL[tid] = mask[(tbase + tid) * B_DIM + b];

    // write chunk 0 into slab0 (swizzle: byte ^= ((row&7)<<4), row&7 == w)
    int wby = (lane * 8) ^ (w << 4);
    #pragma unroll
    for (int i = 0; i < 8; ++i) {
        ushort4 o;
        o.x = bfbits(ld[i].x); o.y = bfbits(ld[i].y);
        o.z = bfbits(ld[i].z); o.w = bfbits(ld[i].w);
        *(ushort4*)((char*)slab0 + (i * 8 + w) * 512 + wby) = o;
    }
    __syncthreads();

    float a8[8] = {0.f, 0.f, 0.f, 0.f, 0.f, 0.f, 0.f, 0.f};
    float M = -3.4e38f, L = 0.f;
    int slice4 = ((lane >> 5) + 2 * w) * 4;      // PV t-base for this thread
    int hpvb = (lane & 31) * 16;                 // PV h byte-base (8 bf16)

    for (int s = 0; s < CHUNKS; ++s) {
        const char* cur = (const char*)((s & 1) ? slab1 : slab0);
        char* nxt = (char*)((s & 1) ? slab0 : slab1);

        // issue next-chunk global loads (write-late after PV)
        if (s < CHUNKS - 1) {
            #pragma unroll
            for (int i = 0; i < 8; ++i) {
                int row = (s + 1) * TCH + i * 8 + w;
                ld[i] = *((const float4*)(mbase + (size_t)row * (B_DIM * H_DIM)) + lane);
            }
        }

        // ---- MFMA: C[a][t], A from persistent regs, B from LDS only ----
        f32x4 acc[2][4];
        #pragma unroll
        for (int mf = 0; mf < 2; ++mf)
            #pragma unroll
            for (int nf = 0; nf < 4; ++nf)
                acc[mf][nf] = (f32x4){0.f, 0.f, 0.f, 0.f};
        #pragma unroll
        for (int kk = 0; kk < 8; ++kk) {
            int kbyte = kk * 64 + lh * 16;
            #pragma unroll
            for (int nf = 0; nf < 4; ++nf) {
                int t = nf * 16 + lr;
                int sw = kbyte ^ ((t & 7) << 4);
                short8 bfr = *(const short8*)(cur + t * 512 + sw);
                acc[0][nf] = __builtin_amdgcn_mfma_f32_16x16x32_bf16(areg[kk][0], bfr, acc[0][nf], 0, 0, 0);
                acc[1][nf] = __builtin_amdgcn_mfma_f32_16x16x32_bf16(areg[kk][1], bfr, acc[1][nf], 0, 0, 0);
            }
        }

        // ---- epilogue: reduce over a (8 in-lane + 2 shuffles) ----
        #pragma unroll
        for (int nf = 0; nf < 4; ++nf) {
            float sv = 0.f;
            #pragma unroll
            for (int mf = 0; mf < 2; ++mf)
                #pragma unroll
                for (int r = 0; r < 4; ++r)
                    sv += wv[mf][r] * fast_tanh(qv[mf][r] + acc[mf][nf][r]);
            sv += __shfl_xor(sv, 16);
            sv += __shfl_xor(sv, 32);
            if (lh == 0) lpart[w * 64 + nf * 16 + lr] = sv;
        }
        __syncthreads();                         // barrier A: lpart ready

        // ---- combine + mask + softmax (every wave, redundant, identical) ----
        float lg = 0.f;
        #pragma unroll
        for (int ww = 0; ww < 8; ++ww) lg += lpart[ww * 64 + lane];
        lg = maskL[s * 64 + lane] ? lg : NEG_INF;
        float mx = lg;
        #pragma unroll
        for (int d = 1; d < 64; d <<= 1) mx = fmaxf(mx, __shfl_xor(mx, d));
        float ex = __expf(lg - mx);
        float sm = ex;
        #pragma unroll
        for (int d = 1; d < 64; d <<= 1) sm += __shfl_xor(sm, d);

        float newM = fmaxf(M, mx);
        float fo = __expf(M - newM);
        L = L * fo + sm * __expf(mx - newM);
        M = newM;
        #pragma unroll
        for (int j = 0; j < 8; ++j) a8[j] *= fo;
        float pself = __expf(lg - M);            // p for t == lane

        // ---- PV from slab[cur]; p via in-wave shuffle ----
        #pragma unroll
        for (int tt = 0; tt < 4; ++tt) {
            int tl = slice4 + tt;
            float pt = __shfl(pself, tl);        // tl in [8w, 8w+8) -> same wave
            int swb = hpvb ^ ((tl & 7) << 4);
            uint4 u = *(const uint4*)(cur + tl * 512 + swb);
            a8[0] += pt * __uint_as_float(u.x << 16);
            a8[1] += pt * __uint_as_float(u.x & 0xFFFF0000u);
            a8[2] += pt * __uint_as_float(u.y << 16);
            a8[3] += pt * __uint_as_float(u.y & 0xFFFF0000u);
            a8[4] += pt * __uint_as_float(u.z << 16);
            a8[5] += pt * __uint_as_float(u.z & 0xFFFF0000u);
            a8[6] += pt * __uint_as_float(u.w << 16);
            a8[7] += pt * __uint_as_float(u.w & 0xFFFF0000u);
        }

        // ---- write next chunk into idle slab (regs arrived long ago) ----
        if (s < CHUNKS - 1) {
            #pragma unroll
            for (int i = 0; i < 8; ++i) {
                ushort4 o;
                o.x = bfbits(ld[i].x); o.y = bfbits(ld[i].y);
                o.z = bfbits(ld[i].z); o.w = bfbits(ld[i].w);
                *(ushort4*)(nxt + (i * 8 + w) * 512 + wby) = o;
            }
        }
        __syncthreads();                         // barrier B: slab swap safe
    }

    // ---- final combine: alias acc2 over slab0 (dead) ----
    float* acc2 = (float*)smem;                  // [16][256]
    int oct = lane & 31, slice = 2 * w + (lane >> 5), h0 = oct * 8;
    *(float4*)(&acc2[slice * 256 + h0])     = (float4){a8[0], a8[1], a8[2], a8[3]};
    *(float4*)(&acc2[slice * 256 + h0 + 4]) = (float4){a8[4], a8[5], a8[6], a8[7]};
    __syncthreads();
    int pidx = g * B_DIM + b;
    if (tid < 256) {
        float ssum = 0.f;
        #pragma unroll
        for (int sl = 0; sl < 16; ++sl) ssum += acc2[sl * 256 + tid];
        part_acc[(size_t)pidx * 256 + tid] = ssum;
    }
    if (tid == 0) { part_m[pidx] = M; part_l[pidx] = L; }
}

// K2: fused merge (4 group-partials -> attn row) + gate GEMV. block = one b.
__global__ void mergegate_kernel(const float* __restrict__ part_m,
                                 const float* __restrict__ part_l,
                                 const float* __restrict__ part_acc,
                                 const float* __restrict__ input,
                                 const float* __restrict__ W_gate,
                                 float* __restrict__ gated) {
    __shared__ float ni[512];
    int b = blockIdx.x, tid = threadIdx.x;
    if (tid >= 256) {
        int k = tid - 256;
        ni[k] = input[b * 256 + k];
    } else {
        int h = tid;
        float M = -3.4e38f;
        #pragma unroll
        for (int c = 0; c < NCHG; ++c) M = fmaxf(M, part_m[c * 64 + b]);
        float L = 0.f, s = 0.f;
        #pragma unroll
        for (int c = 0; c < NCHG; ++c) {
            float sc = __expf(part_m[c * 64 + b] - M);
            L += part_l[c * 64 + b] * sc;
            s += sc * part_acc[(size_t)(c * 64 + b) * 256 + h];
        }
        ni[256 + h] = s / L;
    }
    __syncthreads();
    int j = tid;
    float s0 = 0.f, s1 = 0.f, s2 = 0.f, s3 = 0.f;
    #pragma unroll 4
    for (int k = 0; k < 512; k += 4) {
        s0 += ni[k]     * W_gate[(k)     * 512 + j];
        s1 += ni[k + 1] * W_gate[(k + 1) * 512 + j];
        s2 += ni[k + 2] * W_gate[(k + 2) * 512 + j];
        s3 += ni[k + 3] * W_gate[(k + 3) * 512 + j];
    }
    float s = (s0 + s1) + (s2 + s3);
    gated[b * 512 + j] = ni[j] * fast_sigmoid(s);
}

// K3: GRU cell. grid 256 = (16 b-tiles x 16 h-tiles), block 768.
__global__ __launch_bounds__(768) void gru_kernel(
    const float* __restrict__ gated, const float* __restrict__ state,
    const float* __restrict__ W_ih, const float* __restrict__ W_hh,
    const float* __restrict__ b_ih, const float* __restrict__ b_hh,
    float* __restrict__ out) {
    __shared__ float ld_g[4][512];
    __shared__ float ld_s[4][256];
    __shared__ float xi[3][16][4];
    __shared__ float xh[3][16][4];
    int ht = blockIdx.x & 15, bt = blockIdx.x >> 4;
    int tid = threadIdx.x;
    #pragma unroll
    for (int i = 0; i < 3; ++i) {
        int idx = i * 768 + tid;
        if (idx < 2048) ld_g[idx >> 9][idx & 511] = gated[(bt * 4 + (idx >> 9)) * 512 + (idx & 511)];
    }
    #pragma unroll
    for (int i = 0; i < 2; ++i) {
        int idx = i * 768 + tid;
        if (idx < 1024) ld_s[idx >> 8][idx & 255] = state[(bt * 4 + (idx >> 8)) * 256 + (idx & 255)];
    }

    int gid = tid >> 4, lk = tid & 15;
    int gate = gid >> 4, hl = gid & 15;
    int j = gate * 256 + ht * 16 + hl;

    float4 wi[8], wh[4];
    #pragma unroll
    for (int it = 0; it < 8; ++it)
        wi[it] = *(const float4*)(W_ih + (size_t)j * 512 + it * 64 + lk * 4);
    #pragma unroll
    for (int it = 0; it < 4; ++it)
        wh[it] = *(const float4*)(W_hh + (size_t)j * 256 + it * 64 + lk * 4);
    float bi = b_ih[j], bh = b_hh[j];
    __syncthreads();

    #pragma unroll
    for (int bb = 0; bb < 4; ++bb) {
        float g0 = 0.f, g1 = 0.f;
        #pragma unroll
        for (int it = 0; it < 8; ++it) {
            float4 gv = *(const float4*)(&ld_g[bb][it * 64 + lk * 4]);
            g0 += wi[it].x * gv.x + wi[it].z * gv.z;
            g1 += wi[it].y * gv.y + wi[it].w * gv.w;
        }
        float h0 = 0.f, h1 = 0.f;
        #pragma unroll
        for (int it = 0; it < 4; ++it) {
            float4 sv = *(const float4*)(&ld_s[bb][it * 64 + lk * 4]);
            h0 += wh[it].x * sv.x + wh[it].z * sv.z;
            h1 += wh[it].y * sv.y + wh[it].w * sv.w;
        }
        float gi_ = g0 + g1, gh_ = h0 + h1;
        #pragma unroll
        for (int m = 1; m < 16; m <<= 1) {
            gi_ += __shfl_xor(gi_, m);
            gh_ += __shfl_xor(gh_, m);
        }
        if (lk == 0) { xi[gate][hl][bb] = gi_ + bi; xh[gate][hl][bb] = gh_ + bh; }
    }
    __syncthreads();
    if (tid < 64) {
        int bb = tid >> 4, hl2 = tid & 15;
        float ir = xi[0][hl2][bb], hr = xh[0][hl2][bb];
        float iz = xi[1][hl2][bb], hz = xh[1][hl2][bb];
        float in_ = xi[2][hl2][bb], hn = xh[2][hl2][bb];
        float r = fast_sigmoid(ir + hr);
        float z = fast_sigmoid(iz + hz);
        float n = fast_tanh(in_ + r * hn);
        out[(bt * 4 + bb) * 256 + ht * 16 + hl2] =
            (1.f - z) * n + z * ld_s[bb][ht * 16 + hl2];
    }
}

extern "C" void kernel_launch(void* const* d_in, const int* in_sizes, int n_in,
                              void* d_out, int out_size, void* d_ws, size_t ws_size,
                              hipStream_t stream) {
    const float* input  = (const float*)d_in[0];
    const float* memory = (const float*)d_in[1];
    const int*   mask   = (const int*)d_in[2];
    const float* state  = (const float*)d_in[3];
    const float* W_a1   = (const float*)d_in[4];
    const float* w_a2   = (const float*)d_in[5];
    const float* W_gate = (const float*)d_in[6];
    const float* W_ih   = (const float*)d_in[7];
    const float* W_hh   = (const float*)d_in[8];
    const float* b_ih   = (const float*)d_in[9];
    const float* b_hh   = (const float*)d_in[10];
    float* out = (float*)d_out;

    char* ws = (char*)d_ws;
    unsigned short* WmT = (unsigned short*)(ws + 0);        // 131072 B
    float* qs       = (float*)(ws + 131072);                // 65536 B
    float* gated    = (float*)(ws + 196608);                // 131072 B
    float* part_m   = (float*)(ws + 327680);                // 1024 B
    float* part_l   = (float*)(ws + 331776);                // 1024 B
    float* part_acc = (float*)(ws + 335872);                // 262144 B

    prep_qs_kernel<<<320, 256, 0, stream>>>(W_a1, input, state, WmT, qs);

    (void)hipFuncSetAttribute((const void*)attn_kernel,
                              hipFuncAttributeMaxDynamicSharedMemorySize, 69632);
    attn_kernel<<<dim3(B_DIM, NCHG), 512, 69632, stream>>>(
        memory, mask, WmT, qs, w_a2, part_m, part_l, part_acc);

    mergegate_kernel<<<64, 512, 0, stream>>>(part_m, part_l, part_acc, input, W_gate, gated);
    gru_kernel<<<256, 768, 0, stream>>>(gated, state, W_ih, W_hh, b_ih, b_hh, out);
}